// Round 6
// baseline (73.969 us; speedup 1.0000x reference)
//
#include <hip/hip_runtime.h>
#include <cmath>

#define NPTS 12288
#define NB   64
#define NCH  9
#define NKC  10
#define NBLK 48          // blocks per batch (12288/256)
#define CAPB 16          // pool slots per (block, channel)
#define BIGF 1000000.0f
#define SENT 1e30f

__device__ __forceinline__ float keyf(float x, float y, float z, float m) {
    float n2 = __fadd_rn(__fadd_rn(__fmul_rn(x, x), __fmul_rn(y, y)), __fmul_rn(z, z));
    return __fmul_rn(sqrtf(n2), m);
}

// ---------------------------------------------------------------------------
// K1: self-gating stream. Block = 256 consecutive points of one batch.
// Thread owns one point: 6x float4 -> whole record in regs -> 9 keys.
// Keys to LDS; per-channel block-local threshold T (>= block's 10th smallest,
// via 24-round bit-bisection over ballots); gate key < T (keeps block top-10,
// a superset of this block's global-top-10 members); push to LDS pools;
// single coalesced dump. No global atomics, no seed kernel.
// ---------------------------------------------------------------------------
__global__ __launch_bounds__(256)
void k1_block(const float* __restrict__ kpts, const float* __restrict__ cpt,
              const float* __restrict__ seg,
              float* __restrict__ dv, int* __restrict__ di, int* __restrict__ cnt)
{
    const int blk = blockIdx.x % NBLK;
    const int b   = blockIdx.x / NBLK;
    const int t   = threadIdx.x;
    const int w   = t >> 6, lane = t & 63;
    const int p0  = blk * 256;

    __shared__ float    keys[NCH][256];
    __shared__ unsigned TsU[NCH];
    __shared__ int      lcnt[NCH];
    __shared__ float    lpv[NCH][CAPB];
    __shared__ int      lpi[NCH][CAPB];

    if (t < NCH) lcnt[t] = 0;

    // ---- whole record in registers ----
    size_t base = (size_t)b * NPTS + p0 + t;
    float f[24];
    {
        const float4* kp = (const float4*)(kpts + base * 24);
#pragma unroll
        for (int j = 0; j < 6; ++j) {
            float4 v = kp[j];
            f[4*j] = v.x; f[4*j+1] = v.y; f[4*j+2] = v.z; f[4*j+3] = v.w;
        }
    }
    const float* cp = cpt + base * 3;
    float c0 = cp[0], c1 = cp[1], c2 = cp[2];
    float2 sg = *(const float2*)(seg + base * 2);
    float m = (sg.y > sg.x) ? 1.0f : BIGF;     // argmax==1 <=> seg1>seg0

    float k[NCH];
#pragma unroll
    for (int c = 0; c < 8; ++c) k[c] = keyf(f[3*c], f[3*c+1], f[3*c+2], m);
    k[8] = keyf(c0, c1, c2, m);
#pragma unroll
    for (int c = 0; c < NCH; ++c) keys[c][t] = k[c];
    __syncthreads();

    // ---- per-channel threshold via bit-bisection (wave w: c = w, w+4, [8]) ----
    for (int c = w; c < NCH; c += 4) {
        float4 kv = *(const float4*)&keys[c][4 * lane];
        unsigned u0 = __float_as_uint(kv.x), u1 = __float_as_uint(kv.y);
        unsigned u2 = __float_as_uint(kv.z), u3 = __float_as_uint(kv.w);
        unsigned lo = 0u, hi = 0x7F800000u;   // keys are non-negative floats
        for (int it = 0; it < 24; ++it) {
            unsigned mid = (lo + hi) >> 1;
            int cb = __popcll(__ballot(u0 < mid)) + __popcll(__ballot(u1 < mid))
                   + __popcll(__ballot(u2 < mid)) + __popcll(__ballot(u3 < mid));
            if (cb >= NKC) hi = mid; else lo = mid;
        }
        if (lane == 0) TsU[c] = hi;           // >=10 keys strictly below hi
    }
    __syncthreads();

    // ---- gate + push (keys still in regs) ----
#pragma unroll
    for (int c = 0; c < NCH; ++c) {
        if (__float_as_uint(k[c]) < TsU[c]) {
            int sl = atomicAdd(&lcnt[c], 1);
            if (sl < CAPB) { lpv[c][sl] = k[c]; lpi[c][sl] = p0 + t; }
        }
    }
    __syncthreads();

    // ---- coalesced dump ----
    if (t < NCH * CAPB) {
        int c = t / CAPB, s = t % CAPB;
        int n = lcnt[c]; n = n > CAPB ? CAPB : n;
        size_t g = (((size_t)b * NCH + c) * NBLK + blk) * CAPB + s;
        if (s < n) { dv[g] = lpv[c][s]; di[g] = lpi[c][s]; }
    }
    if (t < NCH) cnt[((size_t)b * NCH + t) * NBLK + blk] = lcnt[t];  // raw (overflow flag)
}

// ---------------------------------------------------------------------------
// K2: one block per b, 576 threads, wave c = channel c. Scan the 48 block
// pools (exact rescan fallback on overflow), per-lane sorted-10 insert with
// (key,idx) stable order, 10-round popmin -> exact reference top_k order.
// Then bit-exact gather/clustering (27 threads) and thread-0 Jacobi SVD.
// ---------------------------------------------------------------------------

#define JROT(P_, Q_) do {                                                      \
    float aa = G[0][P_]*G[0][P_] + G[1][P_]*G[1][P_] + G[2][P_]*G[2][P_];      \
    float bb = G[0][Q_]*G[0][Q_] + G[1][Q_]*G[1][Q_] + G[2][Q_]*G[2][Q_];      \
    float gg = G[0][P_]*G[0][Q_] + G[1][P_]*G[1][Q_] + G[2][P_]*G[2][Q_];      \
    if (fabsf(gg) > 1e-30f) {                                                  \
        float zeta = (bb - aa) / (2.0f * gg);                                  \
        float tt = copysignf(1.0f, zeta) / (fabsf(zeta) + sqrtf(1.0f + zeta*zeta)); \
        float cc = 1.0f / sqrtf(1.0f + tt * tt);                               \
        float ss = cc * tt;                                                    \
        _Pragma("unroll")                                                      \
        for (int ii = 0; ii < 3; ++ii) {                                       \
            float gp = G[ii][P_], gq = G[ii][Q_];                              \
            G[ii][P_] = cc*gp - ss*gq; G[ii][Q_] = ss*gp + cc*gq;              \
            float vp = Vv[ii][P_], vq = Vv[ii][Q_];                            \
            Vv[ii][P_] = cc*vp - ss*vq; Vv[ii][Q_] = ss*vp + cc*vq;            \
        }                                                                      \
    }                                                                          \
} while (0)

#define CSWAP(P_, Q_) do { if (s##P_ < s##Q_) {                                \
    float t_ = s##P_; s##P_ = s##Q_; s##Q_ = t_;                               \
    _Pragma("unroll")                                                          \
    for (int ii = 0; ii < 3; ++ii) {                                           \
        t_ = U[ii][P_];  U[ii][P_]  = U[ii][Q_];  U[ii][Q_]  = t_;             \
        t_ = Vv[ii][P_]; Vv[ii][P_] = Vv[ii][Q_]; Vv[ii][Q_] = t_;             \
    }                                                                          \
} } while (0)

__global__ __launch_bounds__(576)
void k2_final(const float* __restrict__ pcld, const float* __restrict__ kpts,
              const float* __restrict__ cpt,  const float* __restrict__ seg,
              const float* __restrict__ mesh,
              const float* __restrict__ dv,   const int* __restrict__ di,
              const int* __restrict__ cnt,    float* __restrict__ out)
{
    const int b = blockIdx.x, tid = threadIdx.x;
    const int c = tid >> 6, lane = tid & 63;

    __shared__ float scand[NCH][NKC][3];
    __shared__ float voted[NCH][3];
    __shared__ int   scnt[NCH][NBLK];
    __shared__ int   sovf[NCH];

    if (tid < NCH) sovf[tid] = 0;
    __syncthreads();
    if (tid < NCH * NBLK) {
        int cc = tid / NBLK, bb2 = tid % NBLK;
        int n = cnt[((size_t)b * NCH + cc) * NBLK + bb2];
        scnt[cc][bb2] = n > CAPB ? CAPB : n;
        if (n > CAPB) atomicOr(&sovf[cc], 1);
    }
    __syncthreads();

    float v[NKC]; int id[NKC];
#pragma unroll
    for (int j = 0; j < NKC; ++j) { v[j] = SENT; id[j] = 0x7fffffff; }

    if (!sovf[c]) {
        const size_t gb = ((size_t)b * NCH + c) * NBLK * CAPB;
#pragma unroll
        for (int kk = 0; kk < (NBLK * CAPB) / 64; ++kk) {
            int e = lane + 64 * kk;
            int bk = e / CAPB, s = e % CAPB;
            if (s < scnt[c][bk]) {
                float x = dv[gb + e]; int xi = di[gb + e];
                if (x < v[NKC-1] || (x == v[NKC-1] && xi < id[NKC-1])) {
                    v[NKC-1] = x; id[NKC-1] = xi;
#pragma unroll
                    for (int q = NKC - 1; q > 0; --q) {
                        if (v[q] < v[q-1] || (v[q] == v[q-1] && id[q] < id[q-1])) {
                            float tv = v[q]; v[q] = v[q-1]; v[q-1] = tv;
                            int   ti = id[q]; id[q] = id[q-1]; id[q-1] = ti;
                        }
                    }
                }
            }
        }
    } else {
        // exact fallback: full rescan of this channel (statistically never)
        for (int i = lane; i < NPTS; i += 64) {
            size_t base = (size_t)b * NPTS + i;
            float2 sg = *(const float2*)(seg + base * 2);
            float m = (sg.y > sg.x) ? 1.0f : BIGF;
            const float* op = (c < 8) ? (kpts + (base * 8 + c) * 3) : (cpt + base * 3);
            float x = keyf(op[0], op[1], op[2], m);
            if (x < v[NKC-1]) {
                v[NKC-1] = x; id[NKC-1] = i;
#pragma unroll
                for (int q = NKC - 1; q > 0; --q) {
                    if (v[q] < v[q-1] || (v[q] == v[q-1] && id[q] < id[q-1])) {
                        float tv = v[q]; v[q] = v[q-1]; v[q-1] = tv;
                        int   ti = id[q]; id[q] = id[q-1]; id[q-1] = ti;
                    }
                }
            }
        }
    }

    // 10-round popmin across wave; lane r keeps rank r ((key,idx) stable order)
    float keepv = SENT; int keepi = 0;
#pragma unroll
    for (int r = 0; r < NKC; ++r) {
        float mm = v[0]; int mi = id[0];
        float wm = mm;
#pragma unroll
        for (int d = 32; d; d >>= 1) wm = fminf(wm, __shfl_xor(wm, d));
        int c2 = (mm == wm) ? mi : 0x7fffffff;
#pragma unroll
        for (int d = 32; d; d >>= 1) c2 = min(c2, __shfl_xor(c2, d));
        if (mm == wm && mi == c2) {
#pragma unroll
            for (int q = 0; q < NKC - 1; ++q) { v[q] = v[q + 1]; id[q] = id[q + 1]; }
            v[NKC - 1] = SENT; id[NKC - 1] = 0x7fffffff;
        }
        if (lane == r) { keepv = wm; keepi = c2; }
    }

    if (lane < NKC) {
        const int i = keepi;
        size_t base = (size_t)b * NPTS + i;
        const float* pp = pcld + base * 3;
        const float* op = (c < 8) ? (kpts + (base * 8 + c) * 3) : (cpt + base * 3);
        scand[c][lane][0] = __fadd_rn(pp[0], op[0]);
        scand[c][lane][1] = __fadd_rn(pp[1], op[1]);
        scand[c][lane][2] = __fadd_rn(pp[2], op[2]);
    }
    __syncthreads();

    // ---- 27 threads: exact sequential clustering per (channel, coord) ----
    if (tid < NCH * 3) {
        const int cc = tid / 3, d = tid % 3;
        float sum = 0.0f;
#pragma unroll
        for (int q = 0; q < NKC; ++q) sum = __fadd_rn(sum, scand[cc][q][d]);
        float mu = sum / 10.0f;
        float var = 0.0f;
#pragma unroll
        for (int q = 0; q < NKC; ++q) {
            float dq = __fsub_rn(scand[cc][q][d], mu);
            var = __fadd_rn(var, __fmul_rn(dq, dq));
        }
        float sd = sqrtf(var / 10.0f);
        float fs = 0.0f; int cntk = 0;
#pragma unroll
        for (int q = 0; q < NKC; ++q) {
            float x = scand[cc][q][d];
            if (fabsf(__fsub_rn(x, mu)) < sd) {
                fs = __fadd_rn(fs, x);
                if (x != 0.0f) cntk++;
            }
        }
        float res = fs / (float)(cntk > 0 ? cntk : 1);
        voted[cc][d] = res;
        out[768 + ((size_t)b * NCH + cc) * 3 + d] = res;  // kpts_voted
    }
    __syncthreads();

    // ---- thread 0: Kabsch via 3x3 one-sided Jacobi SVD ----
    if (tid == 0) {
        float Ax[9], Ay[9], Az[9], Bx[9], By[9], Bz[9];
#pragma unroll
        for (int n2 = 0; n2 < 9; ++n2) {
            const float* mp = mesh + ((size_t)b * 9 + n2) * 3;
            Ax[n2] = mp[0]; Ay[n2] = mp[1]; Az[n2] = mp[2];
            Bx[n2] = voted[n2][0]; By[n2] = voted[n2][1]; Bz[n2] = voted[n2][2];
        }
        float cax = 0, cay = 0, caz = 0, cbx = 0, cby = 0, cbz = 0;
#pragma unroll
        for (int n2 = 0; n2 < 9; ++n2) {
            cax += Ax[n2]; cay += Ay[n2]; caz += Az[n2];
            cbx += Bx[n2]; cby += By[n2]; cbz += Bz[n2];
        }
        cax /= 9.0f; cay /= 9.0f; caz /= 9.0f;
        cbx /= 9.0f; cby /= 9.0f; cbz /= 9.0f;

        float H[3][3] = {{0,0,0},{0,0,0},{0,0,0}};
#pragma unroll
        for (int n2 = 0; n2 < 9; ++n2) {
            float a0 = Ax[n2]-cax, a1 = Ay[n2]-cay, a2 = Az[n2]-caz;
            float b0 = Bx[n2]-cbx, b1 = By[n2]-cby, b2 = Bz[n2]-cbz;
            H[0][0]+=a0*b0; H[0][1]+=a0*b1; H[0][2]+=a0*b2;
            H[1][0]+=a1*b0; H[1][1]+=a1*b1; H[1][2]+=a1*b2;
            H[2][0]+=a2*b0; H[2][1]+=a2*b1; H[2][2]+=a2*b2;
        }

        float G[3][3], Vv[3][3];
#pragma unroll
        for (int i = 0; i < 3; ++i)
#pragma unroll
            for (int j = 0; j < 3; ++j) {
                G[i][j]  = H[i][j];
                Vv[i][j] = (i == j) ? 1.0f : 0.0f;
            }
        for (int sw = 0; sw < 8; ++sw) { JROT(0,1); JROT(0,2); JROT(1,2); }

        float s0 = sqrtf(G[0][0]*G[0][0] + G[1][0]*G[1][0] + G[2][0]*G[2][0]);
        float s1 = sqrtf(G[0][1]*G[0][1] + G[1][1]*G[1][1] + G[2][1]*G[2][1]);
        float s2 = sqrtf(G[0][2]*G[0][2] + G[1][2]*G[1][2] + G[2][2]*G[2][2]);
        float r0 = 1.0f / fmaxf(s0, 1e-30f);
        float r1 = 1.0f / fmaxf(s1, 1e-30f);
        float r2 = 1.0f / fmaxf(s2, 1e-30f);
        float U[3][3];
#pragma unroll
        for (int i = 0; i < 3; ++i) {
            U[i][0] = G[i][0] * r0; U[i][1] = G[i][1] * r1; U[i][2] = G[i][2] * r2;
        }
        CSWAP(0, 1); CSWAP(1, 2); CSWAP(0, 1);   // descending singular values

        float R0[3][3];
#pragma unroll
        for (int i = 0; i < 3; ++i)
#pragma unroll
            for (int j = 0; j < 3; ++j)
                R0[i][j] = Vv[i][0]*U[j][0] + Vv[i][1]*U[j][1] + Vv[i][2]*U[j][2];
        float det = R0[0][0]*(R0[1][1]*R0[2][2] - R0[1][2]*R0[2][1])
                  - R0[0][1]*(R0[1][0]*R0[2][2] - R0[1][2]*R0[2][0])
                  + R0[0][2]*(R0[1][0]*R0[2][1] - R0[1][1]*R0[2][0]);
        float dsgn = (det >= 0.0f) ? 1.0f : -1.0f;

        float R[3][3];
#pragma unroll
        for (int i = 0; i < 3; ++i)
#pragma unroll
            for (int j = 0; j < 3; ++j) {
                R[i][j] = Vv[i][0]*U[j][0] + Vv[i][1]*U[j][1] + dsgn*Vv[i][2]*U[j][2];
                out[(size_t)b * 9 + i * 3 + j] = R[i][j];
            }
#pragma unroll
        for (int i = 0; i < 3; ++i) {
            float ti = ((i==0)?cbx:(i==1)?cby:cbz)
                     - (R[i][0]*cax + R[i][1]*cay + R[i][2]*caz);
            out[576 + (size_t)b * 3 + i] = ti;
        }
    }
}

extern "C" void kernel_launch(void* const* d_in, const int* in_sizes, int n_in,
                              void* d_out, int out_size, void* d_ws, size_t ws_size,
                              hipStream_t stream)
{
    const float* pcld = (const float*)d_in[0];
    const float* kpts = (const float*)d_in[1];
    const float* cpt  = (const float*)d_in[2];
    const float* seg  = (const float*)d_in[3];
    const float* mesh = (const float*)d_in[4];
    float* out = (float*)d_out;

    // workspace: dv [64*9*48*16] f | di same i | cnt [64*9*48] i  (~3.7 MB)
    const size_t poolN = (size_t)NB * NCH * NBLK * CAPB;
    float* dvp = (float*)d_ws;
    int*   dip = (int*)((char*)d_ws + poolN * sizeof(float));
    int*   cp_ = (int*)((char*)d_ws + poolN * 8ull);

    k1_block<<<NB * NBLK, 256, 0, stream>>>(kpts, cpt, seg, dvp, dip, cp_);
    k2_final<<<NB, 576, 0, stream>>>(pcld, kpts, cpt, seg, mesh, dvp, dip, cp_, out);
}

// Round 7
// 63.675 us; speedup vs baseline: 1.1617x; 1.1617x over previous
//
#include <hip/hip_runtime.h>
#include <cmath>

#define NPTS 12288
#define NB   64
#define NCH  9
#define NKC  10
#define NBLK 48          // blocks per batch (12288/256)
#define CAPB 16          // pool slots per (block, channel)
#define BIGF 1000000.0f
#define SENT 1e30f

__device__ __forceinline__ float keyf(float x, float y, float z, float m) {
    float n2 = __fadd_rn(__fadd_rn(__fmul_rn(x, x), __fmul_rn(y, y)), __fmul_rn(z, z));
    return __fmul_rn(sqrtf(n2), m);
}

// ---------------------------------------------------------------------------
// K1: self-gating stream (unchanged from R6, verified). Block = 256 points.
// Whole record in regs -> 9 keys; per-channel block-local threshold via
// bit-bisection over ballots; gate; LDS pools; coalesced dump.
// ---------------------------------------------------------------------------
__global__ __launch_bounds__(256)
void k1_block(const float* __restrict__ kpts, const float* __restrict__ cpt,
              const float* __restrict__ seg,
              float* __restrict__ dv, int* __restrict__ di, int* __restrict__ cnt)
{
    const int blk = blockIdx.x % NBLK;
    const int b   = blockIdx.x / NBLK;
    const int t   = threadIdx.x;
    const int w   = t >> 6, lane = t & 63;
    const int p0  = blk * 256;

    __shared__ float    keys[NCH][256];
    __shared__ unsigned TsU[NCH];
    __shared__ int      lcnt[NCH];
    __shared__ float    lpv[NCH][CAPB];
    __shared__ int      lpi[NCH][CAPB];

    if (t < NCH) lcnt[t] = 0;

    size_t base = (size_t)b * NPTS + p0 + t;
    float f[24];
    {
        const float4* kp = (const float4*)(kpts + base * 24);
#pragma unroll
        for (int j = 0; j < 6; ++j) {
            float4 v = kp[j];
            f[4*j] = v.x; f[4*j+1] = v.y; f[4*j+2] = v.z; f[4*j+3] = v.w;
        }
    }
    const float* cp = cpt + base * 3;
    float c0 = cp[0], c1 = cp[1], c2 = cp[2];
    float2 sg = *(const float2*)(seg + base * 2);
    float m = (sg.y > sg.x) ? 1.0f : BIGF;     // argmax==1 <=> seg1>seg0

    float k[NCH];
#pragma unroll
    for (int c = 0; c < 8; ++c) k[c] = keyf(f[3*c], f[3*c+1], f[3*c+2], m);
    k[8] = keyf(c0, c1, c2, m);
#pragma unroll
    for (int c = 0; c < NCH; ++c) keys[c][t] = k[c];
    __syncthreads();

    for (int c = w; c < NCH; c += 4) {
        float4 kv = *(const float4*)&keys[c][4 * lane];
        unsigned u0 = __float_as_uint(kv.x), u1 = __float_as_uint(kv.y);
        unsigned u2 = __float_as_uint(kv.z), u3 = __float_as_uint(kv.w);
        unsigned lo = 0u, hi = 0x7F800000u;   // keys are non-negative floats
        for (int it = 0; it < 24; ++it) {
            unsigned mid = (lo + hi) >> 1;
            int cb = __popcll(__ballot(u0 < mid)) + __popcll(__ballot(u1 < mid))
                   + __popcll(__ballot(u2 < mid)) + __popcll(__ballot(u3 < mid));
            if (cb >= NKC) hi = mid; else lo = mid;
        }
        if (lane == 0) TsU[c] = hi;           // >=10 keys strictly below hi
    }
    __syncthreads();

#pragma unroll
    for (int c = 0; c < NCH; ++c) {
        if (__float_as_uint(k[c]) < TsU[c]) {
            int sl = atomicAdd(&lcnt[c], 1);
            if (sl < CAPB) { lpv[c][sl] = k[c]; lpi[c][sl] = p0 + t; }
        }
    }
    __syncthreads();

    if (t < NCH * CAPB) {
        int c = t / CAPB, s = t % CAPB;
        int n = lcnt[c]; n = n > CAPB ? CAPB : n;
        size_t g = (((size_t)b * NCH + c) * NBLK + blk) * CAPB + s;
        if (s < n) { dv[g] = lpv[c][s]; di[g] = lpi[c][s]; }
    }
    if (t < NCH) cnt[((size_t)b * NCH + t) * NBLK + blk] = lcnt[t];  // raw (overflow flag)
}

// ---------------------------------------------------------------------------
// K2: one block per (b, c), 64 threads (1 wave), no LDS, no barriers.
// Scan the 48 pools (12 slots/lane), exact (key,idx)-stable top-10 via
// sorted-insert + 10-round popmin; gather; shuffle coords to lanes 0-2;
// lanes 0-2 run the bit-exact sequential clustering -> voted to ws + out.
// Overflow (cnt > CAPB, measure-zero) -> exact full rescan of the channel.
// ---------------------------------------------------------------------------
__global__ __launch_bounds__(64)
void k2_select(const float* __restrict__ pcld, const float* __restrict__ kpts,
               const float* __restrict__ cpt,  const float* __restrict__ seg,
               const float* __restrict__ dv,   const int* __restrict__ di,
               const int* __restrict__ cnt,    float* __restrict__ vws,
               float* __restrict__ out)
{
    const int bc = blockIdx.x;
    const int b  = bc / NCH, c = bc % NCH;
    const int lane = threadIdx.x;

    int myc = (lane < NBLK) ? cnt[((size_t)b * NCH + c) * NBLK + lane] : 0;
    const bool ovf = __any(myc > CAPB);
    int mycl = myc > CAPB ? CAPB : myc;

    float v[NKC]; int id[NKC];
#pragma unroll
    for (int j = 0; j < NKC; ++j) { v[j] = SENT; id[j] = 0x7fffffff; }

    if (!ovf) {
        const size_t gb = ((size_t)b * NCH + c) * NBLK * CAPB;
#pragma unroll
        for (int kk = 0; kk < (NBLK * CAPB) / 64; ++kk) {
            int e = lane + 64 * kk;
            int bk = e / CAPB, s = e % CAPB;
            int nbk = __shfl(mycl, bk);
            if (s < nbk) {
                float x = dv[gb + e]; int xi = di[gb + e];
                if (x < v[NKC-1] || (x == v[NKC-1] && xi < id[NKC-1])) {
                    v[NKC-1] = x; id[NKC-1] = xi;
#pragma unroll
                    for (int q = NKC - 1; q > 0; --q) {
                        if (v[q] < v[q-1] || (v[q] == v[q-1] && id[q] < id[q-1])) {
                            float tv = v[q]; v[q] = v[q-1]; v[q-1] = tv;
                            int   ti = id[q]; id[q] = id[q-1]; id[q-1] = ti;
                        }
                    }
                }
            }
        }
    } else {
        for (int i = lane; i < NPTS; i += 64) {
            size_t base = (size_t)b * NPTS + i;
            float2 sg = *(const float2*)(seg + base * 2);
            float m = (sg.y > sg.x) ? 1.0f : BIGF;
            const float* op = (c < 8) ? (kpts + (base * 8 + c) * 3) : (cpt + base * 3);
            float x = keyf(op[0], op[1], op[2], m);
            if (x < v[NKC-1]) {
                v[NKC-1] = x; id[NKC-1] = i;
#pragma unroll
                for (int q = NKC - 1; q > 0; --q) {
                    if (v[q] < v[q-1] || (v[q] == v[q-1] && id[q] < id[q-1])) {
                        float tv = v[q]; v[q] = v[q-1]; v[q-1] = tv;
                        int   ti = id[q]; id[q] = id[q-1]; id[q-1] = ti;
                    }
                }
            }
        }
    }

    // 10-round popmin; lane r keeps rank r ((key,idx) stable order)
    float keepv = SENT; int keepi = 0;
#pragma unroll
    for (int r = 0; r < NKC; ++r) {
        float mm = v[0]; int mi = id[0];
        float wm = mm;
#pragma unroll
        for (int d = 32; d; d >>= 1) wm = fminf(wm, __shfl_xor(wm, d));
        int c2 = (mm == wm) ? mi : 0x7fffffff;
#pragma unroll
        for (int d = 32; d; d >>= 1) c2 = min(c2, __shfl_xor(c2, d));
        if (mm == wm && mi == c2) {
#pragma unroll
            for (int q = 0; q < NKC - 1; ++q) { v[q] = v[q + 1]; id[q] = id[q + 1]; }
            v[NKC - 1] = SENT; id[NKC - 1] = 0x7fffffff;
        }
        if (lane == r) { keepv = wm; keepi = c2; }
    }

    // gather candidates on lanes 0..9
    float sx = 0.0f, sy = 0.0f, sz = 0.0f;
    if (lane < NKC) {
        size_t base = (size_t)b * NPTS + keepi;
        const float* pp = pcld + base * 3;
        const float* op = (c < 8) ? (kpts + (base * 8 + c) * 3) : (cpt + base * 3);
        sx = __fadd_rn(pp[0], op[0]);
        sy = __fadd_rn(pp[1], op[1]);
        sz = __fadd_rn(pp[2], op[2]);
    }

    // lanes 0-2: build this coord's 10-array via shuffles (rank order)
    float arr[NKC];
#pragma unroll
    for (int q = 0; q < NKC; ++q) {
        float ax = __shfl(sx, q), ay = __shfl(sy, q), az = __shfl(sz, q);
        arr[q] = (lane == 0) ? ax : (lane == 1) ? ay : az;
    }

    // bit-exact sequential clustering (lanes 0-2, coord = lane)
    float sum = 0.0f;
#pragma unroll
    for (int q = 0; q < NKC; ++q) sum = __fadd_rn(sum, arr[q]);
    float mu = sum / 10.0f;
    float var = 0.0f;
#pragma unroll
    for (int q = 0; q < NKC; ++q) {
        float dq = __fsub_rn(arr[q], mu);
        var = __fadd_rn(var, __fmul_rn(dq, dq));
    }
    float sd = sqrtf(var / 10.0f);
    float fs = 0.0f; int cntk = 0;
#pragma unroll
    for (int q = 0; q < NKC; ++q) {
        float x = arr[q];
        if (fabsf(__fsub_rn(x, mu)) < sd) {
            fs = __fadd_rn(fs, x);
            if (x != 0.0f) cntk++;
        }
    }
    float res = fs / (float)(cntk > 0 ? cntk : 1);

    if (lane < 3) {
        vws[(size_t)bc * 3 + lane] = res;
        out[768 + (size_t)bc * 3 + lane] = res;   // kpts_voted
    }
}

// ---------------------------------------------------------------------------
// K3: one block, 64 threads; lane b does batch b's whole Kabsch SVD in
// registers (all 64 in parallel, uniform control flow, predicated JROT).
// ---------------------------------------------------------------------------

#define JROT(P_, Q_) do {                                                      \
    float aa = G[0][P_]*G[0][P_] + G[1][P_]*G[1][P_] + G[2][P_]*G[2][P_];      \
    float bb = G[0][Q_]*G[0][Q_] + G[1][Q_]*G[1][Q_] + G[2][Q_]*G[2][Q_];      \
    float gg = G[0][P_]*G[0][Q_] + G[1][P_]*G[1][Q_] + G[2][P_]*G[2][Q_];      \
    if (fabsf(gg) > 1e-30f) {                                                  \
        float zeta = (bb - aa) / (2.0f * gg);                                  \
        float tt = copysignf(1.0f, zeta) / (fabsf(zeta) + sqrtf(1.0f + zeta*zeta)); \
        float cc = 1.0f / sqrtf(1.0f + tt * tt);                               \
        float ss = cc * tt;                                                    \
        _Pragma("unroll")                                                      \
        for (int ii = 0; ii < 3; ++ii) {                                       \
            float gp = G[ii][P_], gq = G[ii][Q_];                              \
            G[ii][P_] = cc*gp - ss*gq; G[ii][Q_] = ss*gp + cc*gq;              \
            float vp = Vv[ii][P_], vq = Vv[ii][Q_];                            \
            Vv[ii][P_] = cc*vp - ss*vq; Vv[ii][Q_] = ss*vp + cc*vq;            \
        }                                                                      \
    }                                                                          \
} while (0)

#define CSWAP(P_, Q_) do { if (s##P_ < s##Q_) {                                \
    float t_ = s##P_; s##P_ = s##Q_; s##Q_ = t_;                               \
    _Pragma("unroll")                                                          \
    for (int ii = 0; ii < 3; ++ii) {                                           \
        t_ = U[ii][P_];  U[ii][P_]  = U[ii][Q_];  U[ii][Q_]  = t_;             \
        t_ = Vv[ii][P_]; Vv[ii][P_] = Vv[ii][Q_]; Vv[ii][Q_] = t_;             \
    }                                                                          \
} } while (0)

__global__ __launch_bounds__(64)
void k3_svd(const float* __restrict__ mesh, const float* __restrict__ vws,
            float* __restrict__ out)
{
    const int b = threadIdx.x;   // one batch per lane

    float Ax[9], Ay[9], Az[9], Bx[9], By[9], Bz[9];
#pragma unroll
    for (int n = 0; n < 9; ++n) {
        const float* mp = mesh + ((size_t)b * 9 + n) * 3;
        Ax[n] = mp[0]; Ay[n] = mp[1]; Az[n] = mp[2];
        const float* vp = vws + ((size_t)b * 9 + n) * 3;
        Bx[n] = vp[0]; By[n] = vp[1]; Bz[n] = vp[2];
    }
    float cax = 0, cay = 0, caz = 0, cbx = 0, cby = 0, cbz = 0;
#pragma unroll
    for (int n = 0; n < 9; ++n) {
        cax += Ax[n]; cay += Ay[n]; caz += Az[n];
        cbx += Bx[n]; cby += By[n]; cbz += Bz[n];
    }
    cax /= 9.0f; cay /= 9.0f; caz /= 9.0f;
    cbx /= 9.0f; cby /= 9.0f; cbz /= 9.0f;

    float H[3][3] = {{0,0,0},{0,0,0},{0,0,0}};
#pragma unroll
    for (int n = 0; n < 9; ++n) {
        float a0 = Ax[n]-cax, a1 = Ay[n]-cay, a2 = Az[n]-caz;
        float b0 = Bx[n]-cbx, b1 = By[n]-cby, b2 = Bz[n]-cbz;
        H[0][0]+=a0*b0; H[0][1]+=a0*b1; H[0][2]+=a0*b2;
        H[1][0]+=a1*b0; H[1][1]+=a1*b1; H[1][2]+=a1*b2;
        H[2][0]+=a2*b0; H[2][1]+=a2*b1; H[2][2]+=a2*b2;
    }

    float G[3][3], Vv[3][3];
#pragma unroll
    for (int i = 0; i < 3; ++i)
#pragma unroll
        for (int j = 0; j < 3; ++j) {
            G[i][j]  = H[i][j];
            Vv[i][j] = (i == j) ? 1.0f : 0.0f;
        }
    for (int sw = 0; sw < 8; ++sw) { JROT(0,1); JROT(0,2); JROT(1,2); }

    float s0 = sqrtf(G[0][0]*G[0][0] + G[1][0]*G[1][0] + G[2][0]*G[2][0]);
    float s1 = sqrtf(G[0][1]*G[0][1] + G[1][1]*G[1][1] + G[2][1]*G[2][1]);
    float s2 = sqrtf(G[0][2]*G[0][2] + G[1][2]*G[1][2] + G[2][2]*G[2][2]);
    float r0 = 1.0f / fmaxf(s0, 1e-30f);
    float r1 = 1.0f / fmaxf(s1, 1e-30f);
    float r2 = 1.0f / fmaxf(s2, 1e-30f);
    float U[3][3];
#pragma unroll
    for (int i = 0; i < 3; ++i) {
        U[i][0] = G[i][0] * r0; U[i][1] = G[i][1] * r1; U[i][2] = G[i][2] * r2;
    }
    CSWAP(0, 1); CSWAP(1, 2); CSWAP(0, 1);   // descending singular values

    float R0[3][3];
#pragma unroll
    for (int i = 0; i < 3; ++i)
#pragma unroll
        for (int j = 0; j < 3; ++j)
            R0[i][j] = Vv[i][0]*U[j][0] + Vv[i][1]*U[j][1] + Vv[i][2]*U[j][2];
    float det = R0[0][0]*(R0[1][1]*R0[2][2] - R0[1][2]*R0[2][1])
              - R0[0][1]*(R0[1][0]*R0[2][2] - R0[1][2]*R0[2][0])
              + R0[0][2]*(R0[1][0]*R0[2][1] - R0[1][1]*R0[2][0]);
    float dsgn = (det >= 0.0f) ? 1.0f : -1.0f;

    float R[3][3];
#pragma unroll
    for (int i = 0; i < 3; ++i)
#pragma unroll
        for (int j = 0; j < 3; ++j) {
            R[i][j] = Vv[i][0]*U[j][0] + Vv[i][1]*U[j][1] + dsgn*Vv[i][2]*U[j][2];
            out[(size_t)b * 9 + i * 3 + j] = R[i][j];
        }
#pragma unroll
    for (int i = 0; i < 3; ++i) {
        float ti = ((i==0)?cbx:(i==1)?cby:cbz)
                 - (R[i][0]*cax + R[i][1]*cay + R[i][2]*caz);
        out[576 + (size_t)b * 3 + i] = ti;
    }
}

extern "C" void kernel_launch(void* const* d_in, const int* in_sizes, int n_in,
                              void* d_out, int out_size, void* d_ws, size_t ws_size,
                              hipStream_t stream)
{
    const float* pcld = (const float*)d_in[0];
    const float* kpts = (const float*)d_in[1];
    const float* cpt  = (const float*)d_in[2];
    const float* seg  = (const float*)d_in[3];
    const float* mesh = (const float*)d_in[4];
    float* out = (float*)d_out;

    // workspace: dv [64*9*48*16] f | di same i | cnt [64*9*48] i | vws [64*9*3] f
    const size_t poolN = (size_t)NB * NCH * NBLK * CAPB;
    float* dvp = (float*)d_ws;
    int*   dip = (int*)((char*)d_ws + poolN * sizeof(float));
    int*   cp_ = (int*)((char*)d_ws + poolN * 8ull);
    float* vws = (float*)((char*)d_ws + poolN * 8ull + (size_t)NB * NCH * NBLK * sizeof(int));

    k1_block<<<NB * NBLK, 256, 0, stream>>>(kpts, cpt, seg, dvp, dip, cp_);
    k2_select<<<NB * NCH, 64, 0, stream>>>(pcld, kpts, cpt, seg, dvp, dip, cp_, vws, out);
    k3_svd<<<1, 64, 0, stream>>>(mesh, vws, out);
}